// Round 1
// 4941.833 us; speedup vs baseline: 2.5764x; 2.5764x over previous
//
#include <hip/hip_runtime.h>
#include <cstdint>
#include <cstddef>

#define DEVI __device__ __forceinline__

typedef __attribute__((ext_vector_type(8))) short short8;
typedef __attribute__((ext_vector_type(4))) float floatx4;

DEVI float bf2f(unsigned short u) { union { unsigned int i; float f; } v; v.i = ((unsigned int)u) << 16; return v.f; }
DEVI unsigned short f2bf(float f) {
  union { float f; unsigned int i; } v; v.f = f;
  unsigned int r = v.i + 0x7fffu + ((v.i >> 16) & 1u);
  return (unsigned short)(r >> 16);
}
DEVI float fsig(float x) { return 1.f / (1.f + __expf(-x)); }
DEVI float ftanh(float x) { return 1.f - 2.f / (__expf(2.f * x) + 1.f); }

// agent-scope atomics: ONLY for the q->attention flag + q values inside k1
DEVI unsigned ld32s(const unsigned* p) { return __hip_atomic_load(p, __ATOMIC_RELAXED, __HIP_MEMORY_SCOPE_AGENT); }
DEVI void st32s(unsigned* p, unsigned v) { __hip_atomic_store(p, v, __ATOMIC_RELAXED, __HIP_MEMORY_SCOPE_AGENT); }
DEVI unsigned add32s(unsigned* p, unsigned v) { return __hip_atomic_fetch_add(p, v, __ATOMIC_RELAXED, __HIP_MEMORY_SCOPE_AGENT); }

struct PP {
  const float *c1_0, *c2_0;
  const float *att_b, *dhp_b, *corr_w, *corr_b, *lt_b;
  const float *b_ih1, *b_hh1, *b_ih2, *b_hh2;
  const int* masks;
  float* out;
  unsigned int* SY; float* q0acc;
  const unsigned short* ench; unsigned short* proj; const unsigned short* caps;
  const unsigned short *W1t, *W2t, *dhpWt, *ltWt, *attWt;
  unsigned short* at; unsigned short* h1b; unsigned short* h2b; float* q;
  float *c1ws, *c2ws;
};

DEVI void zero_g(float* g) {
  for (int i = threadIdx.x; i < 128 * 17; i += 1024) g[i] = 0.f;
}

// XOR swizzle: row stride is 256B -> naive layout puts a column in one bank.
// byte ^= (row&7)<<4 spreads 8 rows across 8 distinct 16B slots (G4 recipe).
DEVI int swzb(int row, int kb) { return row * 256 + (kb ^ ((row & 7) << 4)); }

// ---------------------------------------------------------------------------
// LDS-staged GEMM: C[128 x 16] += A[128 x K] * W[16 x K]^T   (K = NC*128)
// 1024 threads / 16 waves. wave = (m-tile 0..7) x (k-half 0..1).
// Per BK=128 chunk: coalesced global->reg (16B/lane contiguous), swizzled
// ds_write_b128, swizzled ds_read_b128 fragments, 2 MFMA 16x16x32 per wave.
// Double-buffered LDS + 2-chunk-deep register prefetch. Partial sums of the
// two k-half waves combined via LDS f32 atomics into g[128*17].
// al(row,k) must return a 16B-aligned pointer to A[row][k..k+8) (bf16).
// ---------------------------------------------------------------------------
template <int NC, typename AL>
DEVI void gemm_lds(float* g, unsigned short (*As)[16384], unsigned short (*Bs)[2048],
                   const unsigned short* Wtile, int ldw, AL al) {
  const int tid = threadIdx.x, wave = tid >> 6, lane = tid & 63;
  // staging coords: A rows sr and sr+64, 16B at k-slot (tid&15)
  const int sr = tid >> 4, sk8 = (tid & 15) << 3;
  const int wA0 = swzb(sr, (tid & 15) << 4);
  const int wA1 = swzb(sr + 64, (tid & 15) << 4);
  const int wB = swzb(sr & 15, (tid & 15) << 4);  // valid for tid<256
  const unsigned short* wrow = Wtile + (size_t)sr * ldw;  // used only tid<256
  // compute coords
  const int m = wave & 7, kh = wave >> 3;
  const int arow = (m << 4) + (lane & 15);
  const int kq = (lane >> 4) << 3;
  const int rA0 = swzb(arow, (kh * 64 + kq) << 1);
  const int rA1 = swzb(arow, (kh * 64 + 32 + kq) << 1);
  const int rB0 = swzb(lane & 15, (kh * 64 + kq) << 1);
  const int rB1 = swzb(lane & 15, (kh * 64 + 32 + kq) << 1);

  short8 aA[2], aB[2], bA, bB;
  floatx4 acc = (floatx4){0.f, 0.f, 0.f, 0.f};

#define LDCHUNK(c, ra, rb)                                        \
  do {                                                            \
    ra[0] = *(const short8*)al(sr, (c)*128 + sk8);                \
    ra[1] = *(const short8*)al(sr + 64, (c)*128 + sk8);           \
    if (tid < 256) rb = *(const short8*)(wrow + (c)*128 + sk8);   \
  } while (0)
#define STCHUNK(b, ra, rb)                                        \
  do {                                                            \
    char* ab_ = (char*)As[b];                                     \
    *(short8*)(ab_ + wA0) = ra[0];                                \
    *(short8*)(ab_ + wA1) = ra[1];                                \
    if (tid < 256) *(short8*)((char*)Bs[b] + wB) = rb;            \
  } while (0)
#define COMPCH(b)                                                 \
  do {                                                            \
    char* ab_ = (char*)As[b];                                     \
    char* bb_ = (char*)Bs[b];                                     \
    short8 x0 = *(const short8*)(ab_ + rA0);                      \
    short8 y0 = *(const short8*)(bb_ + rB0);                      \
    short8 x1 = *(const short8*)(ab_ + rA1);                      \
    short8 y1 = *(const short8*)(bb_ + rB1);                      \
    acc = __builtin_amdgcn_mfma_f32_16x16x32_bf16(x0, y0, acc, 0, 0, 0); \
    acc = __builtin_amdgcn_mfma_f32_16x16x32_bf16(x1, y1, acc, 0, 0, 0); \
  } while (0)

  LDCHUNK(0, aA, bA);
  LDCHUNK(1, aB, bB);
  STCHUNK(0, aA, bA);
  __syncthreads();
#pragma unroll
  for (int c = 0; c < NC; c += 2) {   // NC is even (8/16/20)
    if (c + 2 < NC) LDCHUNK(c + 2, aA, bA);
    COMPCH(0);
    STCHUNK(1, aB, bB);
    __syncthreads();
    if (c + 3 < NC) LDCHUNK(c + 3, aB, bB);
    COMPCH(1);
    if (c + 2 < NC) STCHUNK(0, aA, bA);
    __syncthreads();
  }
#undef LDCHUNK
#undef STCHUNK
#undef COMPCH

  const int col = lane & 15, rr = (lane >> 4) << 2;
#pragma unroll
  for (int r = 0; r < 4; ++r)
    atomicAdd(&g[((m << 4) + rr + r) * 17 + col], acc[r]);
}

DEVI int qidx(int a) { return a + (a >> 6); }

// ================= K1: q (blk<32) | attention (blk 32..159) | out_{t-1} (blk 160..223) =================
__global__ __launch_bounds__(1024, 4) void k1_attn(PP p, int t) {
  __shared__ float g[128 * 17];
  __shared__ unsigned short As[2][16384];
  __shared__ unsigned short Bs[2][2048];
  __shared__ float q_ss[520], corr_ss[520];
  __shared__ float alpha_s[128], e_s[128];
  __shared__ float redv[2];
  const int tid = threadIdx.x, blk = blockIdx.x;
  const int wave = tid >> 6, lane = tid & 63;

  if (blk < 32) {
    // ---- q_t = h2_{t-1} @ dhp_W + dhp_b (only 1<=t<64; t=0 uses precomputed init) ----
    if (t >= 1 && t < 64) {
      zero_g(g);
      const unsigned short* h2p = p.h2b + ((((unsigned)t + 1u) & 1u) << 17);
      auto al = [&](int row, int k) -> const unsigned short* {
        return h2p + ((size_t)row << 10) + k;
      };
      gemm_lds<8>(g, As, Bs, p.dhpWt + (size_t)blk * 16 * 1024, 1024, al);
      __syncthreads();
      for (int e = tid; e < 2048; e += 1024) {
        const int b = e >> 4, col = e & 15, n = blk * 16 + col;
        const float qv = g[b * 17 + col] + p.dhp_b[n];
        st32s((unsigned*)(p.q + b * 512 + n), __float_as_uint(qv));
      }
      __builtin_amdgcn_s_waitcnt(0);
    }
    __syncthreads();
    if (tid == 0) add32s(&p.SY[4], 1u);
  } else if (blk < 160) {
    // ---- attention for batch b ----
    if (t < 64) {
      const int b = blk - 32;
      if (t >= 1) {
        if (tid == 0) {
          while (ld32s(&p.SY[4]) < (unsigned)(32 * (t + 1))) __builtin_amdgcn_s_sleep(1);
        }
        __syncthreads();
        if (tid < 512) q_ss[qidx(tid)] = __uint_as_float(ld32s((const unsigned*)(p.q + b * 512 + tid)));
      } else {
        if (tid < 512) q_ss[qidx(tid)] = p.q[b * 512 + tid];
      }
      if (tid < 512) corr_ss[qidx(tid)] = p.corr_w[tid];
      __syncthreads();
      {  // e[l] = corr . tanh(proj[b,l,:] + q): 8 lanes per l; batch all loads first
        const int l = tid >> 3, l8 = tid & 7;
        const unsigned short* pp_ = p.proj + ((size_t)(b * 128 + l)) * 512 + l8 * 64;
        short8 vv[8];
#pragma unroll
        for (int j = 0; j < 8; ++j) vv[j] = *(const short8*)(pp_ + j * 8);
        float acc = 0.f;
#pragma unroll
        for (int j = 0; j < 8; ++j)
#pragma unroll
          for (int i = 0; i < 8; ++i) {
            const int ap = l8 * 64 + j * 8 + i;
            acc += ftanh(bf2f((unsigned short)vv[j][i]) + q_ss[qidx(ap)]) * corr_ss[qidx(ap)];
          }
        acc += __shfl_down(acc, 4, 8);
        acc += __shfl_down(acc, 2, 8);
        acc += __shfl_down(acc, 1, 8);
        if (l8 == 0) {
          acc += p.corr_b[0];
          if (p.masks[b * 128 + l] != 0) acc = -1e30f;
          e_s[l] = acc;
        }
      }
      __syncthreads();
      if (wave == 0) {
        float m0 = fmaxf(e_s[lane], e_s[lane + 64]);
#pragma unroll
        for (int off = 32; off; off >>= 1) m0 = fmaxf(m0, __shfl_xor(m0, off));
        const float a0 = __expf(e_s[lane] - m0), a1 = __expf(e_s[lane + 64] - m0);
        alpha_s[lane] = a0; alpha_s[lane + 64] = a1;
        float s = a0 + a1;
#pragma unroll
        for (int off = 32; off; off >>= 1) s += __shfl_xor(s, off);
        if (lane == 0) redv[0] = 1.f / s;
      }
      __syncthreads();
      {  // a_t[c] = sum_l alpha[l] * ench[b,l,c]; deep unroll for MLP; PLAIN store
        const float inv = redv[0];
        const unsigned short* pe = p.ench + ((size_t)b << 17) + tid;
        float acc = 0.f;
#pragma unroll 16
        for (int l = 0; l < 128; ++l) acc += alpha_s[l] * bf2f(pe[(size_t)l << 10]);
        p.at[(b << 10) + tid] = f2bf(acc * inv);
      }
    }
  } else {
    // ---- out_{t-1} = tanh(h1_{t-1} @ lt_W + lt_b) (t>=1) ----
    if (t >= 1) {
      const int ob = blk - 160, ot = t - 1;
      zero_g(g);
      const unsigned short* h1 = p.h1b + (((unsigned)ot & 1u) << 17);
      auto al = [&](int row, int k) -> const unsigned short* {
        return h1 + ((size_t)row << 10) + k;
      };
      gemm_lds<8>(g, As, Bs, p.ltWt + (size_t)ob * 16 * 1024, 1024, al);
      __syncthreads();
      for (int e = tid; e < 2048; e += 1024) {
        const int b = e >> 4, col = e & 15, n = ob * 16 + col;
        p.out[(size_t)ot * 131072 + (b << 10) + n] = ftanh(g[b * 17 + col] + p.lt_b[n]);
      }
    }
  }
}

// ================= K2: G1 = [x_t | a_t | h1_{t-1}] @ W1 -> LSTM1 =================
__global__ __launch_bounds__(1024, 4) void k2_g1(PP p, int t) {
  __shared__ float g[128 * 17];
  __shared__ unsigned short As[2][16384];
  __shared__ unsigned short Bs[2][2048];
  const int tid = threadIdx.x, blk = blockIdx.x;
  zero_g(g);
  const unsigned short* caps_t = p.caps + ((size_t)t << 16);
  const unsigned short* h1p = p.h1b + ((((unsigned)t + 1u) & 1u) << 17);
  const unsigned short* at_ = p.at;
  // region boundaries (512, 1536) are 128-aligned -> per-chunk branch folds at compile time
  auto al = [&](int row, int k) -> const unsigned short* {
    if (k < 512) return caps_t + ((size_t)row << 9) + k;
    if (k < 1536) return at_ + ((size_t)row << 10) + (k - 512);
    return h1p + ((size_t)row << 10) + (k - 1536);
  };
  gemm_lds<20>(g, As, Bs, p.W1t + (size_t)blk * 16 * 2560, 2560, al);
  __syncthreads();
  if (tid < 512) {
    const int b = tid >> 2, c = tid & 3;
    const int cidx = b * 1024 + blk * 4 + c;
    const float cprev = (t == 0) ? p.c1_0[cidx] : p.c1ws[cidx];
    const float gi = g[b * 17 + c]      + p.b_ih1[blk * 4 + c]        + p.b_hh1[blk * 4 + c];
    const float gf = g[b * 17 + 4 + c]  + p.b_ih1[1024 + blk * 4 + c] + p.b_hh1[1024 + blk * 4 + c];
    const float gg = g[b * 17 + 8 + c]  + p.b_ih1[2048 + blk * 4 + c] + p.b_hh1[2048 + blk * 4 + c];
    const float go = g[b * 17 + 12 + c] + p.b_ih1[3072 + blk * 4 + c] + p.b_hh1[3072 + blk * 4 + c];
    const float cn = fsig(gf) * cprev + fsig(gi) * ftanh(gg);
    p.c1ws[cidx] = cn;
    p.h1b[(((unsigned)t & 1u) << 17) + (b << 10) + blk * 4 + c] = f2bf(fsig(go) * ftanh(cn));
  }
}

// ================= K3: G2 = [h1_t | h2_{t-1}] @ W2 -> LSTM2 =================
__global__ __launch_bounds__(1024, 4) void k3_g2(PP p, int t) {
  __shared__ float g[128 * 17];
  __shared__ unsigned short As[2][16384];
  __shared__ unsigned short Bs[2][2048];
  const int tid = threadIdx.x, blk = blockIdx.x;
  zero_g(g);
  const unsigned short* h1c = p.h1b + (((unsigned)t & 1u) << 17);
  const unsigned short* h2p = p.h2b + ((((unsigned)t + 1u) & 1u) << 17);
  auto al = [&](int row, int k) -> const unsigned short* {
    if (k < 1024) return h1c + ((size_t)row << 10) + k;
    return h2p + ((size_t)row << 10) + (k - 1024);
  };
  gemm_lds<16>(g, As, Bs, p.W2t + (size_t)blk * 16 * 2048, 2048, al);
  __syncthreads();
  if (tid < 512) {
    const int b = tid >> 2, c = tid & 3;
    const int cidx = b * 1024 + blk * 4 + c;
    const float cprev = (t == 0) ? p.c2_0[cidx] : p.c2ws[cidx];
    const float gi = g[b * 17 + c]      + p.b_ih2[blk * 4 + c]        + p.b_hh2[blk * 4 + c];
    const float gf = g[b * 17 + 4 + c]  + p.b_ih2[1024 + blk * 4 + c] + p.b_hh2[1024 + blk * 4 + c];
    const float gg = g[b * 17 + 8 + c]  + p.b_ih2[2048 + blk * 4 + c] + p.b_hh2[2048 + blk * 4 + c];
    const float go = g[b * 17 + 12 + c] + p.b_ih2[3072 + blk * 4 + c] + p.b_hh2[3072 + blk * 4 + c];
    const float cn = fsig(gf) * cprev + fsig(gi) * ftanh(gg);
    p.c2ws[cidx] = cn;
    p.h2b[(((unsigned)t & 1u) << 17) + (b << 10) + blk * 4 + c] = f2bf(fsig(go) * ftanh(cn));
  }
}

// ================= prep =================
__global__ __launch_bounds__(512) void k_zero(unsigned int* SY, float* q0) {
  SY[threadIdx.x] = 0u;
  q0[threadIdx.x] = 0.f;
}

__global__ __launch_bounds__(256) void k_cvt(const float* caps, const float* ench,
                                             const float* h1_0, const float* h2_0,
                                             unsigned short* o_caps, unsigned short* o_ench,
                                             unsigned short* o_h1, unsigned short* o_h2) {
  const size_t i = (size_t)blockIdx.x * 256 + threadIdx.x;
  if (i < 4194304u) o_caps[i] = f2bf(caps[i]);
  else if (i < 20971520u) o_ench[i - 4194304u] = f2bf(ench[i - 4194304u]);
  else if (i < 21102592u) o_h1[i - 20971520u] = f2bf(h1_0[i - 20971520u]);
  else o_h2[i - 21102592u] = f2bf(h2_0[i - 21102592u]);
}

__global__ __launch_bounds__(256) void k_tr(const float* srcA, const float* srcB, int ksplit,
                                            int K, int stride, int Nrows, int perm,
                                            unsigned short* out, float* q0) {
  __shared__ float lds[64][5];
  const int nbr = Nrows >> 2;
  const int rt = blockIdx.x % nbr, kt = blockIdx.x / nbr;
  const int r0 = rt * 4, k0 = kt * 64;
  int oc0;
  if (perm) { const int nb = r0 >> 4, gg = (r0 & 15) >> 2; oc0 = gg * 1024 + nb * 4; }
  else oc0 = r0;
  {
    const int kk = threadIdx.x >> 2, rr = threadIdx.x & 3;
    const int k = k0 + kk;
    const float* s = (k < ksplit) ? (srcA + (size_t)k * stride) : (srcB + (size_t)(k - ksplit) * stride);
    lds[kk][rr] = s[oc0 + rr];
  }
  __syncthreads();
  if (q0 != nullptr && threadIdx.x < 4) {
    float t = 0.f;
    for (int kk = 0; kk < 64; ++kk) t += lds[kk][threadIdx.x];
    atomicAdd(&q0[oc0 + threadIdx.x], t);
  }
  {
    const int rr = threadIdx.x >> 6, kk = threadIdx.x & 63;
    out[(size_t)(r0 + rr) * K + k0 + kk] = f2bf(lds[kk][rr]);
  }
}

// enc_proj = ench @ att_W + att_b
__global__ __launch_bounds__(1024, 4) void k_proj(PP p) {
  const int tid = threadIdx.x, blk = blockIdx.x;
  const int wave = tid >> 6, lane = tid & 63;
  const int kq = ((lane >> 4) << 3), m16 = lane & 15;
  const int mw = wave & 3, ng = wave >> 2;
  const int mtile = blk * 4 + mw;
  const int mrow = mtile * 16 + m16;
  floatx4 acc[8];
#pragma unroll
  for (int nt = 0; nt < 8; ++nt) acc[nt] = (floatx4){0.f, 0.f, 0.f, 0.f};
  for (int s = 0; s < 32; ++s) {
    const int k = (s << 5) + kq;
    short8 af = *(const short8*)(p.ench + (size_t)mrow * 1024 + k);
#pragma unroll
    for (int nt = 0; nt < 8; ++nt) {
      short8 bf = *(const short8*)(p.attWt + (size_t)(ng * 128 + nt * 16 + m16) * 1024 + k);
      acc[nt] = __builtin_amdgcn_mfma_f32_16x16x32_bf16(af, bf, acc[nt], 0, 0, 0);
    }
  }
#pragma unroll
  for (int nt = 0; nt < 8; ++nt)
#pragma unroll
    for (int r = 0; r < 4; ++r) {
      const int rowg = mtile * 16 + ((lane >> 4) << 2) + r;
      const int col = ng * 128 + nt * 16 + m16;
      p.proj[(size_t)rowg * 512 + col] = f2bf(acc[nt][r] + p.att_b[col]);
    }
}

__global__ __launch_bounds__(1024) void k_qinit(float* q, const float* q0acc, const float* dhp_b) {
  const int i = blockIdx.x * 1024 + threadIdx.x;  // 65536
  const int n = i & 511;
  q[i] = q0acc[n] * (1.f / 1024.f) + dhp_b[n];
}

extern "C" void kernel_launch(void* const* d_in, const int* in_sizes, int n_in,
                              void* d_out, int out_size, void* d_ws, size_t ws_size,
                              hipStream_t stream) {
  const float* enc_hiddens = (const float*)d_in[0];
  const int*   enc_masks   = (const int*)d_in[1];
  const float* h1_0 = (const float*)d_in[2];
  const float* c1_0 = (const float*)d_in[3];
  const float* h2_0 = (const float*)d_in[4];
  const float* c2_0 = (const float*)d_in[5];
  const float* captions = (const float*)d_in[6];
  const float* att_W = (const float*)d_in[7];
  const float* att_b = (const float*)d_in[8];
  const float* dhp_W = (const float*)d_in[9];
  const float* dhp_b = (const float*)d_in[10];
  const float* corr_w = (const float*)d_in[11];
  const float* corr_b = (const float*)d_in[12];
  const float* lt_W = (const float*)d_in[13];
  const float* lt_b = (const float*)d_in[14];
  const float* W_ih1 = (const float*)d_in[15];
  const float* W_hh1 = (const float*)d_in[16];
  const float* b_ih1 = (const float*)d_in[17];
  const float* b_hh1 = (const float*)d_in[18];
  const float* W_ih2 = (const float*)d_in[19];
  const float* W_hh2 = (const float*)d_in[20];
  const float* b_ih2 = (const float*)d_in[21];
  const float* b_hh2 = (const float*)d_in[22];

  uint8_t* w = (uint8_t*)d_ws;
  unsigned int* SY = (unsigned int*)w;
  float* q0acc = (float*)(w + 2048);
  size_t off = 4096;
  unsigned short* ench  = (unsigned short*)(w + off); off += 33554432;
  unsigned short* proj  = (unsigned short*)(w + off); off += 16777216;
  unsigned short* caps  = (unsigned short*)(w + off); off += 8388608;
  unsigned short* W1t   = (unsigned short*)(w + off); off += 20971520;
  unsigned short* W2t   = (unsigned short*)(w + off); off += 16777216;
  unsigned short* dhpWt = (unsigned short*)(w + off); off += 1048576;
  unsigned short* ltWt  = (unsigned short*)(w + off); off += 2097152;
  unsigned short* attWt = (unsigned short*)(w + off); off += 1048576;
  unsigned short* at_   = (unsigned short*)(w + off); off += 262144;
  unsigned short* h1b   = (unsigned short*)(w + off); off += 524288;
  unsigned short* h2b   = (unsigned short*)(w + off); off += 524288;
  float* qb             = (float*)(w + off);          off += 262144;
  float* c1ws           = (float*)(w + off);          off += 524288;
  float* c2ws           = (float*)(w + off);          off += 524288;
  if (ws_size < off) return;

  k_zero<<<1, 512, 0, stream>>>(SY, q0acc);
  k_cvt<<<82944, 256, 0, stream>>>(captions, enc_hiddens, h1_0, h2_0,
                                   caps, ench, h1b + 131072, h2b + 131072);
  k_tr<<<40960, 256, 0, stream>>>(W_ih1, W_hh1, 1536, 2560, 4096, 4096, 1, W1t, nullptr);
  k_tr<<<32768, 256, 0, stream>>>(W_ih2, W_hh2, 1024, 2048, 4096, 4096, 1, W2t, nullptr);
  k_tr<<<2048, 256, 0, stream>>>(dhp_W, dhp_W, 1024, 1024, 512, 512, 0, dhpWt, q0acc);
  k_tr<<<4096, 256, 0, stream>>>(lt_W, lt_W, 1024, 1024, 1024, 1024, 0, ltWt, nullptr);
  k_tr<<<2048, 256, 0, stream>>>(att_W, att_W, 1024, 1024, 512, 512, 0, attWt, nullptr);
  k_qinit<<<64, 1024, 0, stream>>>(qb, q0acc, dhp_b);

  PP p;
  p.c1_0 = c1_0; p.c2_0 = c2_0;
  p.att_b = att_b; p.dhp_b = dhp_b; p.corr_w = corr_w; p.corr_b = corr_b; p.lt_b = lt_b;
  p.b_ih1 = b_ih1; p.b_hh1 = b_hh1; p.b_ih2 = b_ih2; p.b_hh2 = b_hh2;
  p.masks = enc_masks;
  p.out = (float*)d_out;
  p.SY = SY; p.q0acc = q0acc;
  p.ench = ench; p.proj = proj; p.caps = caps;
  p.W1t = W1t; p.W2t = W2t; p.dhpWt = dhpWt; p.ltWt = ltWt; p.attWt = attWt;
  p.at = at_; p.h1b = h1b; p.h2b = h2b; p.q = qb;
  p.c1ws = c1ws; p.c2ws = c2ws;

  k_proj<<<256, 1024, 0, stream>>>(p);

  for (int t = 0; t < 64; ++t) {
    k1_attn<<<224, 1024, 0, stream>>>(p, t);
    k2_g1<<<256, 1024, 0, stream>>>(p, t);
    k3_g2<<<256, 1024, 0, stream>>>(p, t);
  }
  k1_attn<<<224, 1024, 0, stream>>>(p, 64);  // final out_63
}

// Round 2
// 4831.138 us; speedup vs baseline: 2.6355x; 1.0229x over previous
//
#include <hip/hip_runtime.h>
#include <cstdint>
#include <cstddef>

#define DEVI __device__ __forceinline__

typedef __attribute__((ext_vector_type(8))) short short8;
typedef __attribute__((ext_vector_type(4))) float floatx4;
typedef __attribute__((ext_vector_type(4))) unsigned short ushortx4;

DEVI float bf2f(unsigned short u) { union { unsigned int i; float f; } v; v.i = ((unsigned int)u) << 16; return v.f; }
DEVI unsigned short f2bf(float f) {
  union { float f; unsigned int i; } v; v.f = f;
  unsigned int r = v.i + 0x7fffu + ((v.i >> 16) & 1u);
  return (unsigned short)(r >> 16);
}
DEVI float fsig(float x) { return 1.f / (1.f + __expf(-x)); }
DEVI float ftanh(float x) { return 1.f - 2.f / (__expf(2.f * x) + 1.f); }

// agent-scope atomics: ONLY for the q->attention flag + q values inside k1
DEVI unsigned ld32s(const unsigned* p) { return __hip_atomic_load(p, __ATOMIC_RELAXED, __HIP_MEMORY_SCOPE_AGENT); }
DEVI void st32s(unsigned* p, unsigned v) { __hip_atomic_store(p, v, __ATOMIC_RELAXED, __HIP_MEMORY_SCOPE_AGENT); }
DEVI unsigned add32s(unsigned* p, unsigned v) { return __hip_atomic_fetch_add(p, v, __ATOMIC_RELAXED, __HIP_MEMORY_SCOPE_AGENT); }

// Raw workgroup barrier WITHOUT the __syncthreads vmcnt(0) drain (T4):
// ds ops must be complete for cross-wave visibility (lgkmcnt), but global
// loads target REGISTERS here, so in-flight prefetches may cross the barrier.
// Single asm block + memory clobber => nothing memory-related is reordered
// across it by the compiler, and SIInsertWaitcnts can't inject vmcnt(0).
DEVI void bar_nd() { asm volatile("s_waitcnt lgkmcnt(0)\ns_barrier" ::: "memory"); }

struct PP {
  const float *c1_0, *c2_0;
  const float *att_b, *dhp_b, *corr_w, *corr_b, *lt_b;
  const float *b_ih1, *b_hh1, *b_ih2, *b_hh2;
  const int* masks;
  float* out;
  unsigned int* SY; float* q0acc;
  const unsigned short* ench; unsigned short* proj; const unsigned short* caps;
  const unsigned short *W1t, *W2t, *dhpWt, *ltWt, *attWt;
  unsigned short* at; unsigned short* h1b; unsigned short* h2b; float* q;
  float *c1ws, *c2ws;
};

DEVI void zero_g(float* g) {
  for (int i = threadIdx.x; i < 128 * 17; i += 1024) g[i] = 0.f;
}

// XOR swizzle: row stride is 256B -> naive layout puts a column in one bank.
// byte ^= (row&7)<<4 spreads 8 rows across 8 distinct 16B slots (G4 recipe).
DEVI int swzb(int row, int kb) { return row * 256 + (kb ^ ((row & 7) << 4)); }

// ---------------------------------------------------------------------------
// LDS-staged GEMM: C[128 x 16] += A[128 x K] * W[16 x K]^T   (K = NC*128)
// 1024 threads / 16 waves. wave = (m-tile 0..7) x (k-half 0..1).
// Per BK=128 chunk: coalesced global->reg (16B/lane contiguous), swizzled
// ds_write_b128, swizzled ds_read_b128 fragments, 2 MFMA 16x16x32 per wave.
// Double-buffered LDS + 2-chunk-deep register prefetch, raw barriers so the
// prefetch loads stay in flight (no vmcnt(0) drain). Partial sums of the two
// k-half waves combined via LDS f32 atomics into g[128*17].
// ---------------------------------------------------------------------------
template <int NC, typename AL>
DEVI void gemm_lds(float* g, unsigned short (*As)[16384], unsigned short (*Bs)[2048],
                   const unsigned short* Wtile, int ldw, AL al) {
  const int tid = threadIdx.x, wave = tid >> 6, lane = tid & 63;
  // staging coords: A rows sr and sr+64, 16B at k-slot (tid&15)
  const int sr = tid >> 4, sk8 = (tid & 15) << 3;
  const int wA0 = swzb(sr, (tid & 15) << 4);
  const int wA1 = swzb(sr + 64, (tid & 15) << 4);
  const int wB = swzb(sr & 15, (tid & 15) << 4);  // valid for tid<256
  const unsigned short* wrow = Wtile + (size_t)sr * ldw;  // used only tid<256
  // compute coords
  const int m = wave & 7, kh = wave >> 3;
  const int arow = (m << 4) + (lane & 15);
  const int kq = (lane >> 4) << 3;
  const int rA0 = swzb(arow, (kh * 64 + kq) << 1);
  const int rA1 = swzb(arow, (kh * 64 + 32 + kq) << 1);
  const int rB0 = swzb(lane & 15, (kh * 64 + kq) << 1);
  const int rB1 = swzb(lane & 15, (kh * 64 + 32 + kq) << 1);

  short8 aA[2], aB[2], bA, bB;
  floatx4 acc = (floatx4){0.f, 0.f, 0.f, 0.f};

#define LDCHUNK(c, ra, rb)                                        \
  do {                                                            \
    ra[0] = *(const short8*)al(sr, (c)*128 + sk8);                \
    ra[1] = *(const short8*)al(sr + 64, (c)*128 + sk8);           \
    if (tid < 256) rb = *(const short8*)(wrow + (c)*128 + sk8);   \
  } while (0)
#define STCHUNK(b, ra, rb)                                        \
  do {                                                            \
    char* ab_ = (char*)As[b];                                     \
    *(short8*)(ab_ + wA0) = ra[0];                                \
    *(short8*)(ab_ + wA1) = ra[1];                                \
    if (tid < 256) *(short8*)((char*)Bs[b] + wB) = rb;            \
  } while (0)
#define COMPCH(b)                                                 \
  do {                                                            \
    char* ab_ = (char*)As[b];                                     \
    char* bb_ = (char*)Bs[b];                                     \
    short8 x0 = *(const short8*)(ab_ + rA0);                      \
    short8 y0 = *(const short8*)(bb_ + rB0);                      \
    short8 x1 = *(const short8*)(ab_ + rA1);                      \
    short8 y1 = *(const short8*)(bb_ + rB1);                      \
    acc = __builtin_amdgcn_mfma_f32_16x16x32_bf16(x0, y0, acc, 0, 0, 0); \
    acc = __builtin_amdgcn_mfma_f32_16x16x32_bf16(x1, y1, acc, 0, 0, 0); \
  } while (0)

  LDCHUNK(0, aA, bA);
  LDCHUNK(1, aB, bB);
  STCHUNK(0, aA, bA);
  bar_nd();
#pragma unroll
  for (int c = 0; c < NC; c += 2) {   // NC is even (8/16/20)
    if (c + 2 < NC) LDCHUNK(c + 2, aA, bA);
    COMPCH(0);
    STCHUNK(1, aB, bB);
    bar_nd();
    if (c + 3 < NC) LDCHUNK(c + 3, aB, bB);
    COMPCH(1);
    if (c + 2 < NC) STCHUNK(0, aA, bA);
    bar_nd();
  }
#undef LDCHUNK
#undef STCHUNK
#undef COMPCH

  const int col = lane & 15, rr = (lane >> 4) << 2;
#pragma unroll
  for (int r = 0; r < 4; ++r)
    atomicAdd(&g[((m << 4) + rr + r) * 17 + col], acc[r]);
}

DEVI int qidx(int a) { return a + (a >> 6); }

// ================= K1: q (blk<32) | attention (blk 32..159) | out_{t-1} (blk 160..223) =================
__global__ __launch_bounds__(1024, 4) void k1_attn(PP p, int t) {
  __shared__ float g[128 * 17];
  __shared__ unsigned short As[2][16384];
  __shared__ unsigned short Bs[2][2048];
  __shared__ float q_ss[520], corr_ss[520];
  __shared__ float alpha_s[128], e_s[128];
  __shared__ float redv[2];
  const int tid = threadIdx.x, blk = blockIdx.x;
  const int wave = tid >> 6, lane = tid & 63;

  if (blk < 32) {
    // ---- q_t = h2_{t-1} @ dhp_W + dhp_b (only 1<=t<64; t=0 uses precomputed init) ----
    if (t >= 1 && t < 64) {
      zero_g(g);
      const unsigned short* h2p = p.h2b + ((((unsigned)t + 1u) & 1u) << 17);
      auto al = [&](int row, int k) -> const unsigned short* {
        return h2p + ((size_t)row << 10) + k;
      };
      gemm_lds<8>(g, As, Bs, p.dhpWt + (size_t)blk * 16 * 1024, 1024, al);
      __syncthreads();
      for (int e = tid; e < 2048; e += 1024) {
        const int b = e >> 4, col = e & 15, n = blk * 16 + col;
        const float qv = g[b * 17 + col] + p.dhp_b[n];
        st32s((unsigned*)(p.q + b * 512 + n), __float_as_uint(qv));
      }
      __builtin_amdgcn_s_waitcnt(0);
    }
    __syncthreads();
    if (tid == 0) add32s(&p.SY[4], 1u);
  } else if (blk < 160) {
    // ---- attention for batch b ----
    if (t < 64) {
      const int b = blk - 32;
      if (t >= 1) {
        if (tid == 0) {
          while (ld32s(&p.SY[4]) < (unsigned)(32 * (t + 1))) __builtin_amdgcn_s_sleep(1);
        }
        __syncthreads();
        if (tid < 512) q_ss[qidx(tid)] = __uint_as_float(ld32s((const unsigned*)(p.q + b * 512 + tid)));
      } else {
        if (tid < 512) q_ss[qidx(tid)] = p.q[b * 512 + tid];
      }
      if (tid < 512) corr_ss[qidx(tid)] = p.corr_w[tid];
      __syncthreads();
      {  // e[l] = corr . tanh(proj[b,l,:] + q): 8 lanes per l; batch all loads first
        const int l = tid >> 3, l8 = tid & 7;
        const unsigned short* pp_ = p.proj + ((size_t)(b * 128 + l)) * 512 + l8 * 64;
        short8 vv[8];
#pragma unroll
        for (int j = 0; j < 8; ++j) vv[j] = *(const short8*)(pp_ + j * 8);
        float acc = 0.f;
#pragma unroll
        for (int j = 0; j < 8; ++j)
#pragma unroll
          for (int i = 0; i < 8; ++i) {
            const int ap = l8 * 64 + j * 8 + i;
            acc += ftanh(bf2f((unsigned short)vv[j][i]) + q_ss[qidx(ap)]) * corr_ss[qidx(ap)];
          }
        acc += __shfl_down(acc, 4, 8);
        acc += __shfl_down(acc, 2, 8);
        acc += __shfl_down(acc, 1, 8);
        if (l8 == 0) {
          acc += p.corr_b[0];
          if (p.masks[b * 128 + l] != 0) acc = -1e30f;
          e_s[l] = acc;
        }
      }
      __syncthreads();
      if (wave == 0) {
        float m0 = fmaxf(e_s[lane], e_s[lane + 64]);
#pragma unroll
        for (int off = 32; off; off >>= 1) m0 = fmaxf(m0, __shfl_xor(m0, off));
        const float a0 = __expf(e_s[lane] - m0), a1 = __expf(e_s[lane + 64] - m0);
        alpha_s[lane] = a0; alpha_s[lane + 64] = a1;
        float s = a0 + a1;
#pragma unroll
        for (int off = 32; off; off >>= 1) s += __shfl_xor(s, off);
        if (lane == 0) redv[0] = 1.f / s;
      }
      __syncthreads();
      {  // a_t[c] = sum_l alpha[l] * ench[b,l,c]; deep unroll for MLP; PLAIN store
        const float inv = redv[0];
        const unsigned short* pe = p.ench + ((size_t)b << 17) + tid;
        float acc = 0.f;
#pragma unroll 16
        for (int l = 0; l < 128; ++l) acc += alpha_s[l] * bf2f(pe[(size_t)l << 10]);
        p.at[(b << 10) + tid] = f2bf(acc * inv);
      }
    }
  } else {
    // ---- out_{t-1} = tanh(h1_{t-1} @ lt_W + lt_b) (t>=1) ----
    if (t >= 1) {
      const int ob = blk - 160, ot = t - 1;
      zero_g(g);
      const unsigned short* h1 = p.h1b + (((unsigned)ot & 1u) << 17);
      auto al = [&](int row, int k) -> const unsigned short* {
        return h1 + ((size_t)row << 10) + k;
      };
      gemm_lds<8>(g, As, Bs, p.ltWt + (size_t)ob * 16 * 1024, 1024, al);
      __syncthreads();
      for (int e = tid; e < 2048; e += 1024) {
        const int b = e >> 4, col = e & 15, n = ob * 16 + col;
        p.out[(size_t)ot * 131072 + (b << 10) + n] = ftanh(g[b * 17 + col] + p.lt_b[n]);
      }
    }
  }
}

// ================= K2: G1 = [x_t | a_t | h1_{t-1}] @ W1 -> LSTM1 =================
__global__ __launch_bounds__(1024, 4) void k2_g1(PP p, int t) {
  __shared__ float g[128 * 17];
  __shared__ unsigned short As[2][16384];
  __shared__ unsigned short Bs[2][2048];
  const int tid = threadIdx.x, blk = blockIdx.x;
  zero_g(g);
  const unsigned short* caps_t = p.caps + ((size_t)t << 16);
  const unsigned short* h1p = p.h1b + ((((unsigned)t + 1u) & 1u) << 17);
  const unsigned short* at_ = p.at;
  // region boundaries (512, 1536) are 128-aligned -> per-chunk branch folds at compile time
  auto al = [&](int row, int k) -> const unsigned short* {
    if (k < 512) return caps_t + ((size_t)row << 9) + k;
    if (k < 1536) return at_ + ((size_t)row << 10) + (k - 512);
    return h1p + ((size_t)row << 10) + (k - 1536);
  };
  gemm_lds<20>(g, As, Bs, p.W1t + (size_t)blk * 16 * 2560, 2560, al);
  __syncthreads();
  if (tid < 512) {
    const int b = tid >> 2, c = tid & 3;
    const int cidx = b * 1024 + blk * 4 + c;
    const float cprev = (t == 0) ? p.c1_0[cidx] : p.c1ws[cidx];
    const float gi = g[b * 17 + c]      + p.b_ih1[blk * 4 + c]        + p.b_hh1[blk * 4 + c];
    const float gf = g[b * 17 + 4 + c]  + p.b_ih1[1024 + blk * 4 + c] + p.b_hh1[1024 + blk * 4 + c];
    const float gg = g[b * 17 + 8 + c]  + p.b_ih1[2048 + blk * 4 + c] + p.b_hh1[2048 + blk * 4 + c];
    const float go = g[b * 17 + 12 + c] + p.b_ih1[3072 + blk * 4 + c] + p.b_hh1[3072 + blk * 4 + c];
    const float cn = fsig(gf) * cprev + fsig(gi) * ftanh(gg);
    p.c1ws[cidx] = cn;
    p.h1b[(((unsigned)t & 1u) << 17) + (b << 10) + blk * 4 + c] = f2bf(fsig(go) * ftanh(cn));
  }
}

// ================= K3: G2 = [h1_t | h2_{t-1}] @ W2 -> LSTM2 =================
__global__ __launch_bounds__(1024, 4) void k3_g2(PP p, int t) {
  __shared__ float g[128 * 17];
  __shared__ unsigned short As[2][16384];
  __shared__ unsigned short Bs[2][2048];
  const int tid = threadIdx.x, blk = blockIdx.x;
  zero_g(g);
  const unsigned short* h1c = p.h1b + (((unsigned)t & 1u) << 17);
  const unsigned short* h2p = p.h2b + ((((unsigned)t + 1u) & 1u) << 17);
  auto al = [&](int row, int k) -> const unsigned short* {
    if (k < 1024) return h1c + ((size_t)row << 10) + k;
    return h2p + ((size_t)row << 10) + (k - 1024);
  };
  gemm_lds<16>(g, As, Bs, p.W2t + (size_t)blk * 16 * 2048, 2048, al);
  __syncthreads();
  if (tid < 512) {
    const int b = tid >> 2, c = tid & 3;
    const int cidx = b * 1024 + blk * 4 + c;
    const float cprev = (t == 0) ? p.c2_0[cidx] : p.c2ws[cidx];
    const float gi = g[b * 17 + c]      + p.b_ih2[blk * 4 + c]        + p.b_hh2[blk * 4 + c];
    const float gf = g[b * 17 + 4 + c]  + p.b_ih2[1024 + blk * 4 + c] + p.b_hh2[1024 + blk * 4 + c];
    const float gg = g[b * 17 + 8 + c]  + p.b_ih2[2048 + blk * 4 + c] + p.b_hh2[2048 + blk * 4 + c];
    const float go = g[b * 17 + 12 + c] + p.b_ih2[3072 + blk * 4 + c] + p.b_hh2[3072 + blk * 4 + c];
    const float cn = fsig(gf) * cprev + fsig(gi) * ftanh(gg);
    p.c2ws[cidx] = cn;
    p.h2b[(((unsigned)t & 1u) << 17) + (b << 10) + blk * 4 + c] = f2bf(fsig(go) * ftanh(cn));
  }
}

// ================= prep =================
__global__ __launch_bounds__(512) void k_zero(unsigned int* SY, float* q0) {
  SY[threadIdx.x] = 0u;
  q0[threadIdx.x] = 0.f;
}

__global__ __launch_bounds__(256) void k_cvt4(const float* caps, const float* ench,
                                              const float* h1_0, const float* h2_0,
                                              unsigned short* o_caps, unsigned short* o_ench,
                                              unsigned short* o_h1, unsigned short* o_h2) {
  const size_t i = ((size_t)blockIdx.x * 256 + threadIdx.x) << 2;
  const float* s; unsigned short* d; size_t off;
  if (i < 4194304u) { s = caps; d = o_caps; off = i; }
  else if (i < 20971520u) { s = ench; d = o_ench; off = i - 4194304u; }
  else if (i < 21102592u) { s = h1_0; d = o_h1; off = i - 20971520u; }
  else { s = h2_0; d = o_h2; off = i - 21102592u; }
  floatx4 v = *(const floatx4*)(s + off);
  ushortx4 o = { f2bf(v[0]), f2bf(v[1]), f2bf(v[2]), f2bf(v[3]) };
  *(ushortx4*)(d + off) = o;
}

__global__ __launch_bounds__(256) void k_tr(const float* srcA, const float* srcB, int ksplit,
                                            int K, int stride, int Nrows, int perm,
                                            unsigned short* out, float* q0) {
  __shared__ float lds[64][5];
  const int nbr = Nrows >> 2;
  const int rt = blockIdx.x % nbr, kt = blockIdx.x / nbr;
  const int r0 = rt * 4, k0 = kt * 64;
  int oc0;
  if (perm) { const int nb = r0 >> 4, gg = (r0 & 15) >> 2; oc0 = gg * 1024 + nb * 4; }
  else oc0 = r0;
  {
    const int kk = threadIdx.x >> 2, rr = threadIdx.x & 3;
    const int k = k0 + kk;
    const float* s = (k < ksplit) ? (srcA + (size_t)k * stride) : (srcB + (size_t)(k - ksplit) * stride);
    lds[kk][rr] = s[oc0 + rr];
  }
  __syncthreads();
  if (q0 != nullptr && threadIdx.x < 4) {
    float t = 0.f;
    for (int kk = 0; kk < 64; ++kk) t += lds[kk][threadIdx.x];
    atomicAdd(&q0[oc0 + threadIdx.x], t);
  }
  {
    const int rr = threadIdx.x >> 6, kk = threadIdx.x & 63;
    out[(size_t)(r0 + rr) * K + k0 + kk] = f2bf(lds[kk][rr]);
  }
}

// ================= enc_proj = ench @ att_W + att_b (LDS-staged, direct store) =================
// grid 512 = 128 m-slabs x 4 n-slabs. Block computes 128x128. 16 waves =
// 8 m-subtiles x 2 n-halves; each wave 16x64 (4 accs), full K -> no combine.
__global__ __launch_bounds__(1024, 4) void k_proj2(PP p) {
  __shared__ unsigned short As[2][16384];
  __shared__ unsigned short Bs[2][16384];
  const int tid = threadIdx.x, blk = blockIdx.x;
  const int mb = blk >> 2, nb = blk & 3;
  const int m0 = mb << 7, n0 = nb << 7;
  const int wave = tid >> 6, lane = tid & 63;
  const int sr = tid >> 4, sk8 = (tid & 15) << 3;
  const int wL0 = swzb(sr, (tid & 15) << 4);
  const int wL1 = swzb(sr + 64, (tid & 15) << 4);
  const int mw = wave & 7, nh = wave >> 3;
  const int m16 = lane & 15, kq = (lane >> 4) << 3;
  const unsigned short* Ag  = p.ench  + ((size_t)(m0 + sr) << 10);
  const unsigned short* Ag2 = p.ench  + ((size_t)(m0 + sr + 64) << 10);
  const unsigned short* Bg  = p.attWt + ((size_t)(n0 + sr) << 10);
  const unsigned short* Bg2 = p.attWt + ((size_t)(n0 + sr + 64) << 10);

  const int ar = mw * 16 + m16;
  const int aBase = ar * 256, aX = (ar & 7) << 4;
  const int bX = (m16 & 7) << 4;
  int bBase[4];
#pragma unroll
  for (int nf = 0; nf < 4; ++nf) bBase[nf] = (nh * 64 + nf * 16 + m16) * 256;

  floatx4 acc[4];
#pragma unroll
  for (int nf = 0; nf < 4; ++nf) acc[nf] = (floatx4){0.f, 0.f, 0.f, 0.f};

  short8 xa0, xa1, xb0, xb1, ya0, ya1, yb0, yb1;

#define PJLD(c, r0_, r1_, r2_, r3_)                      \
  do {                                                   \
    r0_ = *(const short8*)(Ag + (c) * 128 + sk8);        \
    r1_ = *(const short8*)(Ag2 + (c) * 128 + sk8);       \
    r2_ = *(const short8*)(Bg + (c) * 128 + sk8);        \
    r3_ = *(const short8*)(Bg2 + (c) * 128 + sk8);       \
  } while (0)
#define PJST(b, r0_, r1_, r2_, r3_)                      \
  do {                                                   \
    *(short8*)((char*)As[b] + wL0) = r0_;                \
    *(short8*)((char*)As[b] + wL1) = r1_;                \
    *(short8*)((char*)Bs[b] + wL0) = r2_;                \
    *(short8*)((char*)Bs[b] + wL1) = r3_;                \
  } while (0)
#define PJCOMP(b)                                                        \
  do {                                                                   \
    char* ab_ = (char*)As[b];                                            \
    char* bb_ = (char*)Bs[b];                                            \
    _Pragma("unroll")                                                    \
    for (int ks = 0; ks < 4; ++ks) {                                     \
      const int kb = ks * 64 + (kq << 1);                                \
      short8 af = *(const short8*)(ab_ + aBase + (kb ^ aX));             \
      _Pragma("unroll")                                                  \
      for (int nf = 0; nf < 4; ++nf) {                                   \
        short8 bf = *(const short8*)(bb_ + bBase[nf] + (kb ^ bX));       \
        acc[nf] = __builtin_amdgcn_mfma_f32_16x16x32_bf16(af, bf, acc[nf], 0, 0, 0); \
      }                                                                  \
    }                                                                    \
  } while (0)

  PJLD(0, xa0, xa1, xb0, xb1);
  PJLD(1, ya0, ya1, yb0, yb1);
  PJST(0, xa0, xa1, xb0, xb1);
  bar_nd();
#pragma unroll
  for (int c = 0; c < 8; c += 2) {
    if (c + 2 < 8) PJLD(c + 2, xa0, xa1, xb0, xb1);
    PJCOMP(0);
    PJST(1, ya0, ya1, yb0, yb1);
    bar_nd();
    if (c + 3 < 8) PJLD(c + 3, ya0, ya1, yb0, yb1);
    PJCOMP(1);
    if (c + 2 < 8) PJST(0, xa0, xa1, xb0, xb1);
    bar_nd();
  }
#undef PJLD
#undef PJST
#undef PJCOMP

  const int r0 = (lane >> 4) << 2;
#pragma unroll
  for (int nf = 0; nf < 4; ++nf) {
    const int col = n0 + nh * 64 + nf * 16 + m16;
    const float ab = p.att_b[col];
#pragma unroll
    for (int r = 0; r < 4; ++r) {
      const int row = m0 + mw * 16 + r0 + r;
      p.proj[(size_t)row * 512 + col] = f2bf(acc[nf][r] + ab);
    }
  }
}

__global__ __launch_bounds__(1024) void k_qinit(float* q, const float* q0acc, const float* dhp_b) {
  const int i = blockIdx.x * 1024 + threadIdx.x;  // 65536
  const int n = i & 511;
  q[i] = q0acc[n] * (1.f / 1024.f) + dhp_b[n];
}

extern "C" void kernel_launch(void* const* d_in, const int* in_sizes, int n_in,
                              void* d_out, int out_size, void* d_ws, size_t ws_size,
                              hipStream_t stream) {
  const float* enc_hiddens = (const float*)d_in[0];
  const int*   enc_masks   = (const int*)d_in[1];
  const float* h1_0 = (const float*)d_in[2];
  const float* c1_0 = (const float*)d_in[3];
  const float* h2_0 = (const float*)d_in[4];
  const float* c2_0 = (const float*)d_in[5];
  const float* captions = (const float*)d_in[6];
  const float* att_W = (const float*)d_in[7];
  const float* att_b = (const float*)d_in[8];
  const float* dhp_W = (const float*)d_in[9];
  const float* dhp_b = (const float*)d_in[10];
  const float* corr_w = (const float*)d_in[11];
  const float* corr_b = (const float*)d_in[12];
  const float* lt_W = (const float*)d_in[13];
  const float* lt_b = (const float*)d_in[14];
  const float* W_ih1 = (const float*)d_in[15];
  const float* W_hh1 = (const float*)d_in[16];
  const float* b_ih1 = (const float*)d_in[17];
  const float* b_hh1 = (const float*)d_in[18];
  const float* W_ih2 = (const float*)d_in[19];
  const float* W_hh2 = (const float*)d_in[20];
  const float* b_ih2 = (const float*)d_in[21];
  const float* b_hh2 = (const float*)d_in[22];

  uint8_t* w = (uint8_t*)d_ws;
  unsigned int* SY = (unsigned int*)w;
  float* q0acc = (float*)(w + 2048);
  size_t off = 4096;
  unsigned short* ench  = (unsigned short*)(w + off); off += 33554432;
  unsigned short* proj  = (unsigned short*)(w + off); off += 16777216;
  unsigned short* caps  = (unsigned short*)(w + off); off += 8388608;
  unsigned short* W1t   = (unsigned short*)(w + off); off += 20971520;
  unsigned short* W2t   = (unsigned short*)(w + off); off += 16777216;
  unsigned short* dhpWt = (unsigned short*)(w + off); off += 1048576;
  unsigned short* ltWt  = (unsigned short*)(w + off); off += 2097152;
  unsigned short* attWt = (unsigned short*)(w + off); off += 1048576;
  unsigned short* at_   = (unsigned short*)(w + off); off += 262144;
  unsigned short* h1b   = (unsigned short*)(w + off); off += 524288;
  unsigned short* h2b   = (unsigned short*)(w + off); off += 524288;
  float* qb             = (float*)(w + off);          off += 262144;
  float* c1ws           = (float*)(w + off);          off += 524288;
  float* c2ws           = (float*)(w + off);          off += 524288;
  if (ws_size < off) return;

  k_zero<<<1, 512, 0, stream>>>(SY, q0acc);
  k_cvt4<<<20736, 256, 0, stream>>>(captions, enc_hiddens, h1_0, h2_0,
                                    caps, ench, h1b + 131072, h2b + 131072);
  k_tr<<<40960, 256, 0, stream>>>(W_ih1, W_hh1, 1536, 2560, 4096, 4096, 1, W1t, nullptr);
  k_tr<<<32768, 256, 0, stream>>>(W_ih2, W_hh2, 1024, 2048, 4096, 4096, 1, W2t, nullptr);
  k_tr<<<2048, 256, 0, stream>>>(dhp_W, dhp_W, 1024, 1024, 512, 512, 0, dhpWt, q0acc);
  k_tr<<<4096, 256, 0, stream>>>(lt_W, lt_W, 1024, 1024, 1024, 1024, 0, ltWt, nullptr);
  k_tr<<<2048, 256, 0, stream>>>(att_W, att_W, 1024, 1024, 512, 512, 0, attWt, nullptr);
  k_qinit<<<64, 1024, 0, stream>>>(qb, q0acc, dhp_b);

  PP p;
  p.c1_0 = c1_0; p.c2_0 = c2_0;
  p.att_b = att_b; p.dhp_b = dhp_b; p.corr_w = corr_w; p.corr_b = corr_b; p.lt_b = lt_b;
  p.b_ih1 = b_ih1; p.b_hh1 = b_hh1; p.b_ih2 = b_ih2; p.b_hh2 = b_hh2;
  p.masks = enc_masks;
  p.out = (float*)d_out;
  p.SY = SY; p.q0acc = q0acc;
  p.ench = ench; p.proj = proj; p.caps = caps;
  p.W1t = W1t; p.W2t = W2t; p.dhpWt = dhpWt; p.ltWt = ltWt; p.attWt = attWt;
  p.at = at_; p.h1b = h1b; p.h2b = h2b; p.q = qb;
  p.c1ws = c1ws; p.c2ws = c2ws;

  k_proj2<<<512, 1024, 0, stream>>>(p);

  for (int t = 0; t < 64; ++t) {
    k1_attn<<<224, 1024, 0, stream>>>(p, t);
    k2_g1<<<256, 1024, 0, stream>>>(p, t);
    k3_g2<<<256, 1024, 0, stream>>>(p, t);
  }
  k1_attn<<<224, 1024, 0, stream>>>(p, 64);  // final out_63
}